// Round 5
// baseline (180.545 us; speedup 1.0000x reference)
//
#include <hip/hip_runtime.h>

#define B_ 64
#define I_ 1152
#define C_ 32
#define E_ 16
#define D_ 8
#define IW 8                  // i's per wave
#define NIC (I_/IW)           // 144 i-chunks
#define SCE (B_*C_*E_)        // 32768 s-elements
#define NXCD 8
#define ICX (NIC/NXCD)        // 18 i-chunks per XCD slab

// One-time W transpose into lane-coalesced layout:
// Wt4[((i*8+d)*2+qq)*64 + l] = W[i, c=l&31, d, (l>>5)*8+qq*4 .. +4]
__global__ __launch_bounds__(256)
void transpose_W(const float* __restrict__ W, float4* __restrict__ Wt)
{
  int f = blockIdx.x*256 + threadIdx.x;        // 0 .. 1179647
  int l = f & 63;
  int r = f >> 6;
  int qq = r & 1;
  int d  = (r >> 1) & 7;
  int i  = r >> 4;
  const float4* W4 = (const float4*)W;
  Wt[f] = W4[ ((size_t)(i*32 + (l & 31))*8 + d)*4 + (l >> 5)*2 + qq ];
}

// Barrier-free pass: each wave owns 4 batch rows x IW i's. Recompute
// u_hat[b,i,c,e] = sum_d x[b,i,d]*W[i,c,d,e] from Wt (coalesced), coupling
// coef (uniform or softmax_c of u_hat . vacc), accumulate partial s.
// Lane map: c=l&31, eh=l>>5. No LDS, no __syncthreads.
// Block map: XCD-slab swizzle -- blocks with blockIdx%8==k (round-robin to
// XCD k) cover ic in [k*ICX, (k+1)*ICX), so each XCD streams only a 2.4MB
// slab of Wt (L2-resident). Perf heuristic only; correctness is map-free.
template<bool ROUTE>
__global__ __launch_bounds__(256)
void caps_pass(const float* __restrict__ x, const float4* __restrict__ Wt,
               const float* __restrict__ vacc, float* __restrict__ partial)
{
  const int t    = threadIdx.x;
  const int l    = t & 63;
  const int c    = l & 31;
  const int eh   = l >> 5;
  const int w    = t >> 6;                     // wave in block (0..3)
  const int slot = blockIdx.x >> 3;            // 0..71
  const int ic   = (blockIdx.x & 7) * ICX + (slot >> 2);
  const int bq   = (slot & 3) * 4 + w;         // 0..15
  const int i0   = ic * IW;
  const int b0   = bq * 4;

  float vr[4][8];
  if (ROUTE) {
#pragma unroll
    for (int j = 0; j < 4; ++j) {
      const float4* vp = (const float4*)(vacc + (((size_t)(b0 + j)*C_ + c)*E_ + eh*8));
      float4 a = vp[0], b = vp[1];
      vr[j][0]=a.x; vr[j][1]=a.y; vr[j][2]=a.z; vr[j][3]=a.w;
      vr[j][4]=b.x; vr[j][5]=b.y; vr[j][6]=b.z; vr[j][7]=b.w;
    }
  }

  float acc[4][8];
#pragma unroll
  for (int j = 0; j < 4; ++j)
#pragma unroll
    for (int e = 0; e < 8; ++e) acc[j][e] = 0.f;

  for (int ii = 0; ii < IW; ++ii) {
    const int i = i0 + ii;

    // x for this wave's 4 batch rows (lane-uniform addrs -> L1 broadcast)
    float xv[4][8];
#pragma unroll
    for (int j = 0; j < 4; ++j) {
      const float4* xp = (const float4*)(x + ((size_t)(b0 + j)*I_ + i)*D_);
      float4 a = xp[0], b = xp[1];
      xv[j][0]=a.x; xv[j][1]=a.y; xv[j][2]=a.z; xv[j][3]=a.w;
      xv[j][4]=b.x; xv[j][5]=b.y; xv[j][6]=b.z; xv[j][7]=b.w;
    }

    float uh[4][8];
#pragma unroll
    for (int j = 0; j < 4; ++j)
#pragma unroll
      for (int e = 0; e < 8; ++e) uh[j][e] = 0.f;

    const float4* wrow = Wt + (size_t)i*(D_*2*64) + l;   // + d*128 + qq*64
#pragma unroll
    for (int d = 0; d < D_; ++d) {
      float4 w0 = wrow[d*128];
      float4 w1 = wrow[d*128 + 64];
#pragma unroll
      for (int j = 0; j < 4; ++j) {
        uh[j][0] = fmaf(xv[j][d], w0.x, uh[j][0]);
        uh[j][1] = fmaf(xv[j][d], w0.y, uh[j][1]);
        uh[j][2] = fmaf(xv[j][d], w0.z, uh[j][2]);
        uh[j][3] = fmaf(xv[j][d], w0.w, uh[j][3]);
        uh[j][4] = fmaf(xv[j][d], w1.x, uh[j][4]);
        uh[j][5] = fmaf(xv[j][d], w1.y, uh[j][5]);
        uh[j][6] = fmaf(xv[j][d], w1.z, uh[j][6]);
        uh[j][7] = fmaf(xv[j][d], w1.w, uh[j][7]);
      }
    }

    float coef[4];
    if (ROUTE) {
#pragma unroll
      for (int j = 0; j < 4; ++j) {
        float lg = 0.f;
#pragma unroll
        for (int e = 0; e < 8; ++e) lg = fmaf(uh[j][e], vr[j][e], lg);
        lg += __shfl_xor(lg, 32, 64);            // combine e-halves
        float m = lg;
#pragma unroll
        for (int mk = 16; mk >= 1; mk >>= 1) m = fmaxf(m, __shfl_xor(m, mk, 64));
        float p = __expf(lg - m);
        float s = p;
#pragma unroll
        for (int mk = 16; mk >= 1; mk >>= 1) s += __shfl_xor(s, mk, 64);
        coef[j] = p * __builtin_amdgcn_rcpf(s);
      }
    } else {
#pragma unroll
      for (int j = 0; j < 4; ++j) coef[j] = (1.0f / C_);
    }

#pragma unroll
    for (int j = 0; j < 4; ++j)
#pragma unroll
      for (int e = 0; e < 8; ++e) acc[j][e] = fmaf(coef[j], uh[j][e], acc[j][e]);
  }

  // partial s for this i-chunk: [NIC][B][C][E]
#pragma unroll
  for (int j = 0; j < 4; ++j) {
    size_t base = ((size_t)ic * B_ + (b0 + j)) * (C_*E_) + (size_t)c*E_ + eh*8;
    float4 o0 = {acc[j][0],acc[j][1],acc[j][2],acc[j][3]};
    float4 o1 = {acc[j][4],acc[j][5],acc[j][6],acc[j][7]};
    *(float4*)(partial + base)     = o0;
    *(float4*)(partial + base + 4) = o1;
  }
}

// stage 1: red[ko][idx] = sum of ICX i-chunks
__global__ __launch_bounds__(256)
void reduce1(const float* __restrict__ partial, float* __restrict__ red)
{
  const int idx = blockIdx.x*256 + threadIdx.x;
  const int ko  = blockIdx.y;                     // 0..7
  const float* p = partial + (size_t)(ko*ICX) * SCE + idx;
  float s = 0.f;
#pragma unroll 9
  for (int k = 0; k < ICX; ++k) s += p[(size_t)k * SCE];
  red[(size_t)ko * SCE + idx] = s;
}

// stage 2: sum 8 split-k slabs, squash over e (16-lane groups).
// mode 0: vacc_out = v ; 1: vacc_out = vacc_in + v ; 2: vout = v
__global__ __launch_bounds__(256)
void reduce2(const float* __restrict__ red, const float* __restrict__ vacc_in,
             float* __restrict__ vacc_out, float* __restrict__ vout, int mode)
{
  const int idx = blockIdx.x*256 + threadIdx.x;
  float s = 0.f;
#pragma unroll
  for (int k = 0; k < 8; ++k) s += red[(size_t)k * SCE + idx];
  float sq = s * s;
  sq += __shfl_xor(sq, 1); sq += __shfl_xor(sq, 2);
  sq += __shfl_xor(sq, 4); sq += __shfl_xor(sq, 8);
  float scale = sq / (1.f + sq) / (sqrtf(sq) + 1e-8f);
  float v = scale * s;
  if (mode == 0)      vacc_out[idx] = v;
  else if (mode == 1) vacc_out[idx] = vacc_in[idx] + v;
  else                vout[idx] = v;
}

extern "C" void kernel_launch(void* const* d_in, const int* in_sizes, int n_in,
                              void* d_out, int out_size, void* d_ws, size_t ws_size,
                              hipStream_t stream)
{
  const float* x = (const float*)d_in[0];
  const float* W = (const float*)d_in[1];
  float* out     = (float*)d_out;

  float* partial = (float*)d_ws;                     // NIC*SCE f32 = 18.9 MB
  float* red     = partial + (size_t)NIC * SCE;      // 8*SCE f32 = 1 MB
  float* vacc    = red + 8 * SCE;                    // SCE f32 = 128 KB
  float4* Wt     = (float4*)(vacc + SCE);            // 18.9 MB transposed W

  const int tW = (I_*C_*D_*E_/4) / 256;              // 4608 blocks
  dim3 pg(NXCD * ICX * 4);                           // 576 blocks x 256 thr
  dim3 rg1(SCE/256, 8);                              // 128 x 8
  const int rg2 = SCE/256;                           // 128

  transpose_W<<<tW, 256, 0, stream>>>(W, Wt);

  // iter 0: uniform coefficients (softmax of zeros = 1/32)
  caps_pass<false><<<pg, 256, 0, stream>>>(x, Wt, nullptr, partial);
  reduce1<<<rg1, 256, 0, stream>>>(partial, red);
  reduce2<<<rg2, 256, 0, stream>>>(red, nullptr, vacc, nullptr, 0);
  // iter 1: logits = u_hat . v0
  caps_pass<true ><<<pg, 256, 0, stream>>>(x, Wt, vacc, partial);
  reduce1<<<rg1, 256, 0, stream>>>(partial, red);
  reduce2<<<rg2, 256, 0, stream>>>(red, vacc, vacc, nullptr, 1);
  // iter 2: logits = u_hat . (v0+v1)
  caps_pass<true ><<<pg, 256, 0, stream>>>(x, Wt, vacc, partial);
  reduce1<<<rg1, 256, 0, stream>>>(partial, red);
  reduce2<<<rg2, 256, 0, stream>>>(red, nullptr, nullptr, out, 2);
}